// Round 10
// baseline (143.316 us; speedup 1.0000x reference)
//
#include <hip/hip_runtime.h>
#include <hip/hip_bf16.h>

constexpr int BATCH = 4;
constexpr int SEQ   = 1024;
constexpr int DM    = 512;     // model dim = HEADS*HDIM
constexpr int NH    = 8;
constexpr int HD    = 64;
constexpr int NQKV  = 1536;    // q(512) + k(512) + v(512) fused projection width

typedef unsigned short u16;
typedef __attribute__((ext_vector_type(8))) __bf16 bf8;
typedef __attribute__((ext_vector_type(4))) __bf16 bf4;
typedef __attribute__((ext_vector_type(4))) float  f4;
typedef __attribute__((ext_vector_type(16))) float f16v;

#define MFMA16(a, b, c) __builtin_amdgcn_mfma_f32_16x16x32_bf16(a, b, c, 0, 0, 0)
#define MFMA32(a, b, c) __builtin_amdgcn_mfma_f32_32x32x16_bf16(a, b, c, 0, 0, 0)

// 0.125 (1/sqrt(64)) * log2(e): q pre-scale so softmax uses exp2 directly
#define QSC 0.18033688f

static __device__ __forceinline__ u16 f2b(float f) {
    union { float f; unsigned u; } v; v.f = f;
    unsigned r = v.u + 0x7FFFu + ((v.u >> 16) & 1u);   // RNE; inputs never NaN
    return (u16)(r >> 16);
}
static __device__ __forceinline__ float b2f(u16 x) {
    union { unsigned u; float f; } v; v.u = (unsigned)x << 16;   // bf16->f32 exact
    return v.f;
}
static __device__ __forceinline__ float fexp2(float x) {
    return __builtin_amdgcn_exp2f(x);
}
// async global->LDS, 16 B per lane (dst = wave-uniform base + lane*16)
static __device__ __forceinline__ void gl_lds16(const void* g, void* l) {
    __builtin_amdgcn_global_load_lds(
        (const __attribute__((address_space(1))) void*)g,
        (__attribute__((address_space(3))) void*)l, 16, 0, 0);
}
// pack two f32 -> one u32 of 2 bf16 (RNE), single VOP3
static __device__ __forceinline__ unsigned cvtpk_bf16(float lo, float hi) {
    unsigned r;
    asm("v_cvt_pk_bf16_f32 %0, %1, %2" : "=v"(r) : "v"(lo), "v"(hi));
    return r;
}
// swap a's hi-32-lane half with b's lo-32-lane half
static __device__ __forceinline__ void swap32(unsigned &a, unsigned &b) {
    asm("v_permlane32_swap_b32 %0, %1" : "+v"(a), "+v"(b));
}

// ---------------------------------------------------------------------------
// Fused prep: one launch does all fp32->bf16 converts + weight transposes.
// ---------------------------------------------------------------------------
__device__ __forceinline__ void tcvt_tile(const float* __restrict__ in,
                                          u16* __restrict__ out,
                                          int R, int C, int bx, int by, int tid,
                                          float (*t)[33]) {
    int r0 = by * 32, c0 = bx * 32;
    int lc = tid & 31, lr = tid >> 5;   // lr in [0,8)
    #pragma unroll
    for (int p = 0; p < 4; p++) {
        int r = lr + p * 8;
        t[r][lc] = in[(size_t)(r0 + r) * C + c0 + lc];
    }
    __syncthreads();
    #pragma unroll
    for (int p = 0; p < 4; p++) {
        int r = lr + p * 8;
        out[(size_t)(c0 + r) * R + r0 + lc] = f2b(t[lc][r]);
    }
}

__global__ __launch_bounds__(256)
void prep(const float* __restrict__ x, const float* __restrict__ Wq,
          const float* __restrict__ Wkv, const float* __restrict__ Wout,
          const float* __restrict__ pemb,
          u16* __restrict__ xb, u16* __restrict__ qkvw,
          u16* __restrict__ Woutt, u16* __restrict__ pembb) {
    __shared__ float t[32][33];
    const int blk = blockIdx.x, tid = threadIdx.x;
    if (blk < 2048) {
        int i = (blk * 256 + tid) * 4;
        float4 v = *(const float4*)(x + i);
        ushort4 o = {f2b(v.x), f2b(v.y), f2b(v.z), f2b(v.w)};
        *(ushort4*)(xb + i) = o;
    } else if (blk < 2113) {
        int i = ((blk - 2048) * 256 + tid) * 4;
        if (i < 1025 * HD) {
            float4 v = *(const float4*)(pemb + i);
            ushort4 o = {f2b(v.x), f2b(v.y), f2b(v.z), f2b(v.w)};
            *(ushort4*)(pembb + i) = o;
        }
    } else if (blk < 2369) {
        int l = blk - 2113;
        tcvt_tile(Wq, qkvw, 512, 512, l & 15, l >> 4, tid, t);
    } else if (blk < 2881) {
        int l = blk - 2369;
        tcvt_tile(Wkv, qkvw + 512 * 512, 512, 1024, l & 31, l >> 5, tid, t);
    } else {
        int l = blk - 2881;
        tcvt_tile(Wout, Woutt, 512, 512, l & 15, l >> 4, tid, t);
    }
}

// ---------------------------------------------------------------------------
// MFMA GEMM: C[M,N] = A[M,K] @ Bt[N,K]^T  (bf16 in, fp32 acc)
// Templated on BN (tile = 64 x BN). BK=64 as 2x 32-wide sub-tiles (m97
// layout). 256 threads = 4 waves; per-wave output 32 x BN/2.
//   BN=128: QKV projection.  BN=64: output projection (512 blocks = 2/CU).
// Mode 1 (Cf!=null): fp32 out + bias. Mode 2 (qtb/ktb/vtb): QKV packing.
// ---------------------------------------------------------------------------
template<int BN>
__global__ __launch_bounds__(256)
void gemm_bt(const u16* __restrict__ A, const u16* __restrict__ Bt,
             int M, int N, int K,
             float* __restrict__ Cf, const float* __restrict__ bias,
             __bf16* __restrict__ qtb, __bf16* __restrict__ ktb,
             __bf16* __restrict__ vtb) {
    constexpr int NJ = BN / 32;          // B-frags per wave
    __shared__ __align__(16) u16 As[2][64][32];
    __shared__ __align__(16) u16 Bs[2][BN][32];
    const int tid = threadIdx.x, w = tid >> 6, lane = tid & 63;
    const int l15 = lane & 15, l4 = lane >> 4;
    const int wr = (w >> 1) * 32, wc = (w & 1) * (BN / 2);
    const int bm = blockIdx.y * 64, bn = blockIdx.x * BN;

    f4 acc[2][NJ];
    #pragma unroll
    for (int i = 0; i < 2; i++)
        #pragma unroll
        for (int j = 0; j < NJ; j++) acc[i][j] = (f4){0.f, 0.f, 0.f, 0.f};

    const int rS = lane >> 2;          // row within a 16-row staging group
    const int cS = (lane & 3) * 8;     // col (u16) within the 32-wide row

    for (int k0 = 0; k0 < K; k0 += 64) {
        #pragma unroll
        for (int ks = 0; ks < 2; ks++) {
            gl_lds16(A + (size_t)(bm + w * 16 + rS) * K + k0 + ks * 32 + cS,
                     &As[ks][w * 16][0]);
            #pragma unroll
            for (int rb = 0; rb < BN / 4; rb += 16)
                gl_lds16(Bt + (size_t)(bn + w * (BN / 4) + rb + rS) * K
                             + k0 + ks * 32 + cS,
                         &Bs[ks][w * (BN / 4) + rb][0]);
        }
        __syncthreads();
        #pragma unroll
        for (int ks = 0; ks < 2; ks++) {
            bf8 af[2], bf[NJ];
            #pragma unroll
            for (int i = 0; i < 2; i++)
                af[i] = *(const bf8*)&As[ks][wr + i * 16 + l15][l4 * 8];
            #pragma unroll
            for (int j = 0; j < NJ; j++)
                bf[j] = *(const bf8*)&Bs[ks][wc + j * 16 + l15][l4 * 8];
            #pragma unroll
            for (int i = 0; i < 2; i++)
                #pragma unroll
                for (int j = 0; j < NJ; j++)
                    acc[i][j] = MFMA16(af[i], bf[j], acc[i][j]);
        }
        __syncthreads();
    }
    #pragma unroll
    for (int i = 0; i < 2; i++)
        #pragma unroll
        for (int j = 0; j < NJ; j++) {
            const int col = bn + wc + j * 16 + l15;
            const int row0 = bm + wr + i * 16 + l4 * 4;
            if (Cf) {
                #pragma unroll
                for (int reg = 0; reg < 4; reg++)
                    Cf[(size_t)(row0 + reg) * N + col] = acc[i][j][reg] + bias[col];
            } else if (col < 512) {
                int h = col >> 6, d = col & 63;
                #pragma unroll
                for (int reg = 0; reg < 4; reg++) {
                    int row = row0 + reg;
                    int b = row >> 10, t = row & 1023;
                    qtb[((((size_t)(b * 8 + h)) << 10 | t) << 6) | d] =
                        (__bf16)(acc[i][j][reg] * QSC);
                }
            } else if (col < 1024) {
                int h = (col >> 6) - 8, d = col & 63;
                #pragma unroll
                for (int reg = 0; reg < 4; reg++) {
                    int row = row0 + reg;
                    int b = row >> 10, t = row & 1023;
                    ktb[((((size_t)(b * 8 + h)) << 10 | t) << 6) | d] =
                        (__bf16)acc[i][j][reg];
                }
            } else {
                int h = (col >> 6) - 16, d = col & 63;
                int b = row0 >> 10, t = row0 & 1023;   // 4 rows share b (t aligned 4)
                __bf16 pk[4];
                #pragma unroll
                for (int reg = 0; reg < 4; reg++) pk[reg] = (__bf16)acc[i][j][reg];
                *(ushort4*)&vtb[(((size_t)(b * 8 + h) * 64 + d) << 10) | t] =
                    *(ushort4*)pk;
            }
        }
}

// ---------------------------------------------------------------------------
// Fused MFMA flash attention — 32x32 quadrant structure + REGISTER-direct K/V
// (R8 hypothesis, de-risked resubmit: the token-pasted ATTN_STEP macro is
// replaced by a plain #pragma-unroll'ed 16-iter loop; cur/nxt = i&1 constant-
// fold under full unroll so all register-array indices stay compile-time).
// Insight: each wave's K/V fragments are 16B-contiguous, 64B-line-aligned
// direct global accesses (wq-pairs issue identical addresses -> L1 dedup).
// The LDS K/V staging (global->reg->LDS->reg) was a pure copy pipeline.
// K/V frags are PREFETCHED INTO REGISTERS one full iteration ahead (~1500cy
// in flight vs R1's failed ~100-instr slack), consumed right after the
// barrier, so QK^T starts instantly. Issue order pj -> K -> V so the
// refresh's pj wait (counted vmcnt) leaves K/V in flight. LDS holds ONLY the
// qdot ring (36,864 B); the barrier guards only the ring wt-handoff.
// Ring epoch check: same-iter ring reads hit rows [193,255]u[0,63] mod 256,
// refresh writes [129,193) — disjoint; barrier separates epochs.
// Grid: x = bh (XCD L2 locality), y = s0/64.
// ---------------------------------------------------------------------------
__global__ __launch_bounds__(256)
void attn_mfma(const u16* __restrict__ qtb, const u16* __restrict__ ktb,
               const u16* __restrict__ vtb, const u16* __restrict__ pembb,
               __bf16* __restrict__ ctxb) {
    __shared__ __align__(16) __bf16 Qd[256][72];    // qdot ring [j&255][s]

    const int tid = threadIdx.x, w = tid >> 6, lane = tid & 63;
    const int l31 = lane & 31, hi = lane >> 5;
    const int wq = w >> 1, wt = w & 1;
    const int bh = blockIdx.x, b = bh >> 3;
    const int s0 = blockIdx.y * 64;

    // Q frags (B-operand for swapped QK^T, A-operand for ring refresh)
    bf8 qb[4];
    {
        const u16* qp = qtb + ((size_t)bh * SEQ + s0 + wq * 32 + l31) * HD + hi * 8;
        #pragma unroll
        for (int st = 0; st < 4; st++) qb[st] = *(const bf8*)(qp + st * 16);
    }

    const u16* kbase = ktb + (size_t)bh * SEQ * HD;   // [t][d] packed
    const u16* vbase = vtb + (size_t)bh * HD * SEQ;   // [d][t]
    // per-lane fragment base pointers (add t offset per tile)
    const u16* kp  = kbase + (size_t)(wt * 32 + l31) * HD + hi * 8;
    const u16* vp0 = vbase + (size_t)l31 * SEQ        + wt * 32 + hi * 8;
    const u16* vp1 = vbase + (size_t)(32 + l31) * SEQ + wt * 32 + hi * 8;

    // ---- K/V register double-buffers; preload tile 0 ----
    bf8 kf[2][4], vf[2][4];
    #pragma unroll
    for (int st = 0; st < 4; st++) kf[0][st] = *(const bf8*)(kp + st * 16);
    vf[0][0] = *(const bf8*)(vp0);
    vf[0][1] = *(const bf8*)(vp0 + 16);
    vf[0][2] = *(const bf8*)(vp1);
    vf[0][3] = *(const bf8*)(vp1 + 16);

    // ---- init ring: j in [s0+449, +127], wave covers (s=wq-half, j=wt-half)
    #pragma unroll
    for (int pass = 0; pass < 2; pass++) {
        const int jr = s0 + 449 + pass * 64 + wt * 32 + l31;
        const int jc = min(1024, max(0, jr));
        const u16* pp = pembb + (size_t)jc * HD + hi * 8;
        f16v acc;
        #pragma unroll
        for (int r = 0; r < 16; r++) acc[r] = 0.f;
        #pragma unroll
        for (int st = 0; st < 4; st++) {
            bf8 pj = *(const bf8*)(pp + st * 16);
            acc = MFMA32(qb[st], pj, acc);
        }
        #pragma unroll
        for (int o4 = 0; o4 < 4; o4++) {
            bf4 pk;
            #pragma unroll
            for (int r = 0; r < 4; r++) pk[r] = (__bf16)acc[o4 * 4 + r];
            *(bf4*)&Qd[jr & 255][wq * 32 + o4 * 8 + hi * 4] = pk;
        }
    }

    float l_lane = 0.f;
    f16v oo[2];
    #pragma unroll
    for (int dt = 0; dt < 2; dt++)
        #pragma unroll
        for (int r = 0; r < 16; r++) oo[dt][r] = 0.f;

    __syncthreads();   // ring init visible to both wt-waves

    #pragma unroll
    for (int i = 0; i < 16; i++) {
        const int cur = i & 1, nxt = cur ^ 1;   // compile-time after unroll
        const int t0 = i * 64, t1 = t0 + 64;
        const bool pre = (i < 15);
        // ---- prefetch tile i+1 into regs (pj first, then K, then V) ----
        bf8 pj0, pj1, pj2, pj3;
        const int jrn = s0 + 449 - 64 * (i + 1) + wt * 32 + l31;
        if (pre) {
            const int jc = min(1024, max(0, jrn));
            const u16* pp = pembb + (size_t)jc * HD + hi * 8;
            pj0 = *(const bf8*)(pp);
            pj1 = *(const bf8*)(pp + 16);
            pj2 = *(const bf8*)(pp + 32);
            pj3 = *(const bf8*)(pp + 48);
            kf[nxt][0] = *(const bf8*)(kp + (size_t)t1 * HD);
            kf[nxt][1] = *(const bf8*)(kp + (size_t)t1 * HD + 16);
            kf[nxt][2] = *(const bf8*)(kp + (size_t)t1 * HD + 32);
            kf[nxt][3] = *(const bf8*)(kp + (size_t)t1 * HD + 48);
            vf[nxt][0] = *(const bf8*)(vp0 + t1);
            vf[nxt][1] = *(const bf8*)(vp0 + t1 + 16);
            vf[nxt][2] = *(const bf8*)(vp1 + t1);
            vf[nxt][3] = *(const bf8*)(vp1 + t1 + 16);
        }

        // ---- ring gather (W(i) slots, committed before last barrier) ----
        const int jcst = (s0 - t0 + 512) + wq * 32 + l31 - wt * 32 - 4 * hi;
        const u16* qdc = (const u16*)&Qd[0][0] + wq * 32 + l31;
        u16 rg[16];
        #pragma unroll
        for (int r = 0; r < 16; r++) {
            const int pat = (r & 3) + 8 * (r >> 2);
            rg[r] = qdc[((jcst - pat) & 255) * 72];
        }

        // ---- QK^T from registers — starts immediately at the barrier ----
        __builtin_amdgcn_s_setprio(1);
        f16v s16;
        #pragma unroll
        for (int r = 0; r < 16; r++) s16[r] = 0.f;
        s16 = MFMA32(kf[cur][0], qb[0], s16);
        s16 = MFMA32(kf[cur][1], qb[1], s16);
        s16 = MFMA32(kf[cur][2], qb[2], s16);
        s16 = MFMA32(kf[cur][3], qb[3], s16);
        __builtin_amdgcn_s_setprio(0);

        // ---- softmax half 0 -> pa0 -> 2 PV MFMAs ----
        float p[16];
        float la = 0.f, lb = 0.f;
        #pragma unroll
        for (int r = 0; r < 8; r++) {
            float pv = fexp2(s16[r] + b2f(rg[r]));
            p[r] = pv; la += pv;
        }
        unsigned w00 = cvtpk_bf16(p[0], p[1]), w01 = cvtpk_bf16(p[2], p[3]);
        unsigned w10 = cvtpk_bf16(p[4], p[5]), w11 = cvtpk_bf16(p[6], p[7]);
        swap32(w00, w10); swap32(w01, w11);
        union { unsigned u[4]; bf8 v; } pa0, pa1;
        pa0.u[0] = w00; pa0.u[1] = w01; pa0.u[2] = w10; pa0.u[3] = w11;
        __builtin_amdgcn_s_setprio(1);
        oo[0] = MFMA32(pa0.v, vf[cur][0], oo[0]);
        oo[1] = MFMA32(pa0.v, vf[cur][2], oo[1]);
        __builtin_amdgcn_s_setprio(0);

        // ---- refresh MFMA chain (pj), completes under sm1/PV1 ----
        f16v rf;
        if (pre) {
            #pragma unroll
            for (int r = 0; r < 16; r++) rf[r] = 0.f;
            rf = MFMA32(qb[0], pj0, rf);
            rf = MFMA32(qb[1], pj1, rf);
            rf = MFMA32(qb[2], pj2, rf);
            rf = MFMA32(qb[3], pj3, rf);
        }

        // ---- softmax half 1 -> pa1 -> 2 PV MFMAs ----
        #pragma unroll
        for (int r = 8; r < 16; r++) {
            float pv = fexp2(s16[r] + b2f(rg[r]));
            p[r] = pv; lb += pv;
        }
        unsigned w20 = cvtpk_bf16(p[8],  p[9]),  w21 = cvtpk_bf16(p[10], p[11]);
        unsigned w30 = cvtpk_bf16(p[12], p[13]), w31 = cvtpk_bf16(p[14], p[15]);
        swap32(w20, w30); swap32(w21, w31);
        pa1.u[0] = w20; pa1.u[1] = w21; pa1.u[2] = w30; pa1.u[3] = w31;
        __builtin_amdgcn_s_setprio(1);
        oo[0] = MFMA32(pa1.v, vf[cur][1], oo[0]);
        oo[1] = MFMA32(pa1.v, vf[cur][3], oo[1]);
        __builtin_amdgcn_s_setprio(0);
        l_lane += la + lb;

        // ---- tail: ring b64 writes only ----
        if (pre) {
            #pragma unroll
            for (int o4 = 0; o4 < 4; o4++) {
                bf4 pk;
                #pragma unroll
                for (int r = 0; r < 4; r++) pk[r] = (__bf16)rf[o4 * 4 + r];
                *(bf4*)&Qd[jrn & 255][wq * 32 + o4 * 8 + hi * 4] = pk;
            }
        }
        __syncthreads();   // ring W(i+1) visible; slots of W(i) released
    }

    // ---- epilogue: cross-half l, cross-wave O reduce (ring LDS reused),
    //      normalize, store ----
    float lsum = l_lane + __shfl_xor(l_lane, 32);
    float* Os = (float*)&Qd[0][0];          // ring is dead; reuse as scratch
    float* Ls = Os + 4096;
    if (lane < 32) Ls[(wq * 2 + wt) * 32 + l31] = lsum;
    if (wt == 0) {
        #pragma unroll
        for (int dt = 0; dt < 2; dt++)
            #pragma unroll
            for (int r = 0; r < 16; r++) {
                const int q = (r & 3) + 8 * (r >> 2) + 4 * hi;
                Os[(wq * 32 + q) * 64 + dt * 32 + l31] = oo[dt][r];
            }
    }
    __syncthreads();
    if (wt == 1) {
        const int h = bh & 7;
        #pragma unroll
        for (int r = 0; r < 16; r++) {
            const int q = (r & 3) + 8 * (r >> 2) + 4 * hi;
            const float li = 1.f / (Ls[wq * 64 + q] + Ls[wq * 64 + 32 + q]);
            #pragma unroll
            for (int dt = 0; dt < 2; dt++) {
                float v = (oo[dt][r] + Os[(wq * 32 + q) * 64 + dt * 32 + l31]) * li;
                ctxb[(size_t)(b * SEQ + s0 + wq * 32 + q) * DM + h * HD + dt * 32 + l31]
                    = (__bf16)v;
            }
        }
    }
}

// ---------------------------------------------------------------------------
extern "C" void kernel_launch(void* const* d_in, const int* in_sizes, int n_in,
                              void* d_out, int out_size, void* d_ws, size_t ws_size,
                              hipStream_t stream) {
    const float* x    = (const float*)d_in[0];
    // d_in[1] attn_mask: unused by the reference computation
    const float* Wq   = (const float*)d_in[2];
    const float* Wkv  = (const float*)d_in[3];
    const float* Wout = (const float*)d_in[4];
    const float* bout = (const float*)d_in[5];
    const float* pemb = (const float*)d_in[6];
    float* out = (float*)d_out;

    const int M = BATCH * SEQ;   // 4096
    u16* p = (u16*)d_ws;
    u16* xb    = p; p += (size_t)M * DM;          // 4096x512
    u16* qkvw  = p; p += (size_t)NQKV * DM;       // 1536x512 (Wq^T ++ Wkv^T)
    u16* Woutt = p; p += (size_t)DM * DM;         // 512x512
    u16* pembb = p; p += (size_t)1025 * HD;       // 1025x64
    u16* qtb   = p; p += (size_t)M * DM;          // 32x1024x64 packed q (scaled)
    u16* ktb   = p; p += (size_t)M * DM;          // 32x1024x64 packed K
    u16* vtb   = p; p += (size_t)M * DM;          // 32x64x1024 transposed V
    u16* ctxb  = p; p += (size_t)M * DM;          // 4096x512

    prep<<<3137, 256, 0, stream>>>(x, Wq, Wkv, Wout, pemb, xb, qkvw, Woutt, pembb);

    // QKV projection with fused q-scale / K-pack / V-transpose epilogue
    gemm_bt<128><<<dim3(NQKV / 128, M / 64), 256, 0, stream>>>(
        xb, qkvw, M, NQKV, DM, nullptr, nullptr,
        (__bf16*)qtb, (__bf16*)ktb, (__bf16*)vtb);

    // fused attention -> ctx; grid x=bh for XCD L2 locality
    attn_mfma<<<dim3(BATCH * NH, SEQ / 64), 256, 0, stream>>>(
        qtb, ktb, vtb, pembb, (__bf16*)ctxb);

    // out = ctx @ Wout + bout  (BN=64: 512 blocks = 2/CU vs 1/CU at BN=128)
    gemm_bt<64><<<dim3(DM / 64, M / 64), 256, 0, stream>>>(
        ctxb, Woutt, M, DM, DM, out, bout, nullptr, nullptr, nullptr);
}

// Round 11
// 127.501 us; speedup vs baseline: 1.1240x; 1.1240x over previous
//
#include <hip/hip_runtime.h>
#include <hip/hip_bf16.h>

constexpr int BATCH = 4;
constexpr int SEQ   = 1024;
constexpr int DM    = 512;     // model dim = HEADS*HDIM
constexpr int NH    = 8;
constexpr int HD    = 64;
constexpr int NQKV  = 1536;    // q(512) + k(512) + v(512) fused projection width

typedef unsigned short u16;
typedef __attribute__((ext_vector_type(8))) __bf16 bf8;
typedef __attribute__((ext_vector_type(4))) __bf16 bf4;
typedef __attribute__((ext_vector_type(4))) float  f4;
typedef __attribute__((ext_vector_type(16))) float f16v;

#define MFMA16(a, b, c) __builtin_amdgcn_mfma_f32_16x16x32_bf16(a, b, c, 0, 0, 0)
#define MFMA32(a, b, c) __builtin_amdgcn_mfma_f32_32x32x16_bf16(a, b, c, 0, 0, 0)

// 0.125 (1/sqrt(64)) * log2(e): q pre-scale so softmax uses exp2 directly
#define QSC 0.18033688f

static __device__ __forceinline__ u16 f2b(float f) {
    union { float f; unsigned u; } v; v.f = f;
    unsigned r = v.u + 0x7FFFu + ((v.u >> 16) & 1u);   // RNE; inputs never NaN
    return (u16)(r >> 16);
}
static __device__ __forceinline__ float b2f(u16 x) {
    union { unsigned u; float f; } v; v.u = (unsigned)x << 16;   // bf16->f32 exact
    return v.f;
}
static __device__ __forceinline__ float fexp2(float x) {
    return __builtin_amdgcn_exp2f(x);
}
// async global->LDS, 16 B per lane (dst = wave-uniform base + lane*16)
static __device__ __forceinline__ void gl_lds16(const void* g, void* l) {
    __builtin_amdgcn_global_load_lds(
        (const __attribute__((address_space(1))) void*)g,
        (__attribute__((address_space(3))) void*)l, 16, 0, 0);
}
// pack two f32 -> one u32 of 2 bf16 (RNE), single VOP3
static __device__ __forceinline__ unsigned cvtpk_bf16(float lo, float hi) {
    unsigned r;
    asm("v_cvt_pk_bf16_f32 %0, %1, %2" : "=v"(r) : "v"(lo), "v"(hi));
    return r;
}
// swap a's hi-32-lane half with b's lo-32-lane half
static __device__ __forceinline__ void swap32(unsigned &a, unsigned &b) {
    asm("v_permlane32_swap_b32 %0, %1" : "+v"(a), "+v"(b));
}

// ---------------------------------------------------------------------------
// Fused prep: one launch does all fp32->bf16 converts + weight transposes.
// ---------------------------------------------------------------------------
__device__ __forceinline__ void tcvt_tile(const float* __restrict__ in,
                                          u16* __restrict__ out,
                                          int R, int C, int bx, int by, int tid,
                                          float (*t)[33]) {
    int r0 = by * 32, c0 = bx * 32;
    int lc = tid & 31, lr = tid >> 5;   // lr in [0,8)
    #pragma unroll
    for (int p = 0; p < 4; p++) {
        int r = lr + p * 8;
        t[r][lc] = in[(size_t)(r0 + r) * C + c0 + lc];
    }
    __syncthreads();
    #pragma unroll
    for (int p = 0; p < 4; p++) {
        int r = lr + p * 8;
        out[(size_t)(c0 + r) * R + r0 + lc] = f2b(t[lc][r]);
    }
}

__global__ __launch_bounds__(256)
void prep(const float* __restrict__ x, const float* __restrict__ Wq,
          const float* __restrict__ Wkv, const float* __restrict__ Wout,
          const float* __restrict__ pemb,
          u16* __restrict__ xb, u16* __restrict__ qkvw,
          u16* __restrict__ Woutt, u16* __restrict__ pembb) {
    __shared__ float t[32][33];
    const int blk = blockIdx.x, tid = threadIdx.x;
    if (blk < 2048) {
        int i = (blk * 256 + tid) * 4;
        float4 v = *(const float4*)(x + i);
        ushort4 o = {f2b(v.x), f2b(v.y), f2b(v.z), f2b(v.w)};
        *(ushort4*)(xb + i) = o;
    } else if (blk < 2113) {
        int i = ((blk - 2048) * 256 + tid) * 4;
        if (i < 1025 * HD) {
            float4 v = *(const float4*)(pemb + i);
            ushort4 o = {f2b(v.x), f2b(v.y), f2b(v.z), f2b(v.w)};
            *(ushort4*)(pembb + i) = o;
        }
    } else if (blk < 2369) {
        int l = blk - 2113;
        tcvt_tile(Wq, qkvw, 512, 512, l & 15, l >> 4, tid, t);
    } else if (blk < 2881) {
        int l = blk - 2369;
        tcvt_tile(Wkv, qkvw + 512 * 512, 512, 1024, l & 31, l >> 5, tid, t);
    } else {
        int l = blk - 2881;
        tcvt_tile(Wout, Woutt, 512, 512, l & 15, l >> 4, tid, t);
    }
}

// ---------------------------------------------------------------------------
// MFMA GEMM: C[M,N] = A[M,K] @ Bt[N,K]^T  (bf16 in, fp32 acc)
// Templated on BN (tile = 64 x BN). BK=64 as 2x 32-wide sub-tiles (m97
// layout). 256 threads = 4 waves; per-wave output 32 x BN/2.
//   BN=128: QKV projection.  BN=64: output projection (512 blocks = 2/CU).
// Mode 1 (Cf!=null): fp32 out + bias. Mode 2 (qtb/ktb/vtb): QKV packing.
// ---------------------------------------------------------------------------
template<int BN>
__global__ __launch_bounds__(256)
void gemm_bt(const u16* __restrict__ A, const u16* __restrict__ Bt,
             int M, int N, int K,
             float* __restrict__ Cf, const float* __restrict__ bias,
             __bf16* __restrict__ qtb, __bf16* __restrict__ ktb,
             __bf16* __restrict__ vtb) {
    constexpr int NJ = BN / 32;          // B-frags per wave
    __shared__ __align__(16) u16 As[2][64][32];
    __shared__ __align__(16) u16 Bs[2][BN][32];
    const int tid = threadIdx.x, w = tid >> 6, lane = tid & 63;
    const int l15 = lane & 15, l4 = lane >> 4;
    const int wr = (w >> 1) * 32, wc = (w & 1) * (BN / 2);
    const int bm = blockIdx.y * 64, bn = blockIdx.x * BN;

    f4 acc[2][NJ];
    #pragma unroll
    for (int i = 0; i < 2; i++)
        #pragma unroll
        for (int j = 0; j < NJ; j++) acc[i][j] = (f4){0.f, 0.f, 0.f, 0.f};

    const int rS = lane >> 2;          // row within a 16-row staging group
    const int cS = (lane & 3) * 8;     // col (u16) within the 32-wide row

    for (int k0 = 0; k0 < K; k0 += 64) {
        #pragma unroll
        for (int ks = 0; ks < 2; ks++) {
            gl_lds16(A + (size_t)(bm + w * 16 + rS) * K + k0 + ks * 32 + cS,
                     &As[ks][w * 16][0]);
            #pragma unroll
            for (int rb = 0; rb < BN / 4; rb += 16)
                gl_lds16(Bt + (size_t)(bn + w * (BN / 4) + rb + rS) * K
                             + k0 + ks * 32 + cS,
                         &Bs[ks][w * (BN / 4) + rb][0]);
        }
        __syncthreads();
        #pragma unroll
        for (int ks = 0; ks < 2; ks++) {
            bf8 af[2], bf[NJ];
            #pragma unroll
            for (int i = 0; i < 2; i++)
                af[i] = *(const bf8*)&As[ks][wr + i * 16 + l15][l4 * 8];
            #pragma unroll
            for (int j = 0; j < NJ; j++)
                bf[j] = *(const bf8*)&Bs[ks][wc + j * 16 + l15][l4 * 8];
            #pragma unroll
            for (int i = 0; i < 2; i++)
                #pragma unroll
                for (int j = 0; j < NJ; j++)
                    acc[i][j] = MFMA16(af[i], bf[j], acc[i][j]);
        }
        __syncthreads();
    }
    #pragma unroll
    for (int i = 0; i < 2; i++)
        #pragma unroll
        for (int j = 0; j < NJ; j++) {
            const int col = bn + wc + j * 16 + l15;
            const int row0 = bm + wr + i * 16 + l4 * 4;
            if (Cf) {
                #pragma unroll
                for (int reg = 0; reg < 4; reg++)
                    Cf[(size_t)(row0 + reg) * N + col] = acc[i][j][reg] + bias[col];
            } else if (col < 512) {
                int h = col >> 6, d = col & 63;
                #pragma unroll
                for (int reg = 0; reg < 4; reg++) {
                    int row = row0 + reg;
                    int b = row >> 10, t = row & 1023;
                    qtb[((((size_t)(b * 8 + h)) << 10 | t) << 6) | d] =
                        (__bf16)(acc[i][j][reg] * QSC);
                }
            } else if (col < 1024) {
                int h = (col >> 6) - 8, d = col & 63;
                #pragma unroll
                for (int reg = 0; reg < 4; reg++) {
                    int row = row0 + reg;
                    int b = row >> 10, t = row & 1023;
                    ktb[((((size_t)(b * 8 + h)) << 10 | t) << 6) | d] =
                        (__bf16)acc[i][j][reg];
                }
            } else {
                int h = (col >> 6) - 16, d = col & 63;
                int b = row0 >> 10, t = row0 & 1023;   // 4 rows share b (t aligned 4)
                __bf16 pk[4];
                #pragma unroll
                for (int reg = 0; reg < 4; reg++) pk[reg] = (__bf16)acc[i][j][reg];
                *(ushort4*)&vtb[(((size_t)(b * 8 + h) * 64 + d) << 10) | t] =
                    *(ushort4*)pk;
            }
        }
}

// ---------------------------------------------------------------------------
// Fused MFMA flash attention — verified-best R7 structure (124.26us total)
// + MFMA chain-split (R11). R10 proved direct-global K/V regresses 20us:
// the LDS staging is a coalescing+broadcast stage, not a copy pipeline
// (cooperative contiguous-row loads vs 128B/2KB-stride per-frag gathers).
// R7 base: swapped QK^T (lane-local softmax), cvt_pk + permlane32 P->A
// frags, reg-staged double-buffered K/V ([72]-padded LDS), hoisted LDS
// loads, mid-iter K/V commit, softmax/PV interleave, setprio on MFMA
// clusters, LDS qdot ring [j&255][s] with b64 refresh writes, one barrier
// per K-tile. R11 edit: QK^T and ring-refresh each used 4 MFMA32 chained
// through ONE accumulator (4x dependent latency on the serial path); split
// into 2+2 over two accumulators — the combine folds into the softmax add
// (QK^T) or costs 16 v_add_f32 hidden under PV (refresh).
// Grid: x = bh (XCD L2 locality), y = s0/64. LDS = 73,728 B -> 2 blocks/CU.
// ---------------------------------------------------------------------------
__global__ __launch_bounds__(256)
void attn_mfma(const u16* __restrict__ qtb, const u16* __restrict__ ktb,
               const u16* __restrict__ vtb, const u16* __restrict__ pembb,
               __bf16* __restrict__ ctxb) {
    __shared__ __align__(16) __bf16 Kb[2][64][72];  // K tiles [t][d]
    __shared__ __align__(16) __bf16 Vb[2][64][72];  // V tiles [d][t]
    __shared__ __align__(16) __bf16 Qd[256][72];    // qdot ring [j&255][s]

    const int tid = threadIdx.x, w = tid >> 6, lane = tid & 63;
    const int l31 = lane & 31, hi = lane >> 5;
    const int wq = w >> 1, wt = w & 1;
    const int bh = blockIdx.x, b = bh >> 3;
    const int s0 = blockIdx.y * 64;

    // Q frags (B-operand for swapped QK^T, A-operand for ring refresh)
    bf8 qb[4];
    {
        const u16* qp = qtb + ((size_t)bh * SEQ + s0 + wq * 32 + l31) * HD + hi * 8;
        #pragma unroll
        for (int st = 0; st < 4; st++) qb[st] = *(const bf8*)(qp + st * 16);
    }

    // ---- init ring: j in [s0+449, +127], wave covers (s=wq-half, j=wt-half)
    #pragma unroll
    for (int pass = 0; pass < 2; pass++) {
        const int jr = s0 + 449 + pass * 64 + wt * 32 + l31;
        const int jc = min(1024, max(0, jr));
        const u16* pp = pembb + (size_t)jc * HD + hi * 8;
        f16v acc;
        #pragma unroll
        for (int r = 0; r < 16; r++) acc[r] = 0.f;
        #pragma unroll
        for (int st = 0; st < 4; st++) {
            bf8 pj = *(const bf8*)(pp + st * 16);
            acc = MFMA32(qb[st], pj, acc);
        }
        #pragma unroll
        for (int o4 = 0; o4 < 4; o4++) {
            bf4 pk;
            #pragma unroll
            for (int r = 0; r < 4; r++) pk[r] = (__bf16)acc[o4 * 4 + r];
            *(bf4*)&Qd[jr & 255][wq * 32 + o4 * 8 + hi * 4] = pk;
        }
    }

    float l_lane = 0.f;
    f16v oo[2];
    #pragma unroll
    for (int dt = 0; dt < 2; dt++)
        #pragma unroll
        for (int r = 0; r < 16; r++) oo[dt][r] = 0.f;

    const u16* kbase = ktb + (size_t)bh * SEQ * HD;   // [t][d] packed
    const u16* vbase = vtb + (size_t)bh * HD * SEQ;   // [d][t]
    const int sr = tid >> 3, sc = (tid & 7) * 8;

    // ---- stage tile 0 into buf 0 ----
    *(bf8*)&Kb[0][sr][sc]      = *(const bf8*)(kbase + (size_t)sr * HD + sc);
    *(bf8*)&Kb[0][sr + 32][sc] = *(const bf8*)(kbase + (size_t)(sr + 32) * HD + sc);
    *(bf8*)&Vb[0][sr][sc]      = *(const bf8*)(vbase + (size_t)sr * SEQ + sc);
    *(bf8*)&Vb[0][sr + 32][sc] = *(const bf8*)(vbase + (size_t)(sr + 32) * SEQ + sc);
    __syncthreads();

    for (int i = 0; i < 16; i++) {
        const int cur = i & 1, nxt = cur ^ 1;
        const int t0 = i * 64, t1 = t0 + 64;
        const bool pre = (i < 15);
        bf8 kr0, kr1, vr0, vr1, pj0, pj1, pj2, pj3;
        const int jrn = s0 + 449 - 64 * (i + 1) + wt * 32 + l31;
        if (pre) {
            kr0 = *(const bf8*)(kbase + (size_t)(t1 + sr) * HD + sc);
            kr1 = *(const bf8*)(kbase + (size_t)(t1 + sr + 32) * HD + sc);
            vr0 = *(const bf8*)(vbase + (size_t)sr * SEQ + t1 + sc);
            vr1 = *(const bf8*)(vbase + (size_t)(sr + 32) * SEQ + t1 + sc);
            const int jc = min(1024, max(0, jrn));
            const u16* pp = pembb + (size_t)jc * HD + hi * 8;
            pj0 = *(const bf8*)(pp);
            pj1 = *(const bf8*)(pp + 16);
            pj2 = *(const bf8*)(pp + 32);
            pj3 = *(const bf8*)(pp + 48);
        }

        // ---- ALL LDS loads up front: K-frags, ring gather, V-frags ----
        bf8 ka[4];
        #pragma unroll
        for (int st = 0; st < 4; st++)
            ka[st] = *(const bf8*)&Kb[cur][wt * 32 + l31][st * 16 + hi * 8];
        const int jcst = (s0 - t0 + 512) + wq * 32 + l31 - wt * 32 - 4 * hi;
        const u16* qdc = (const u16*)&Qd[0][0] + wq * 32 + l31;
        u16 rg[16];
        #pragma unroll
        for (int r = 0; r < 16; r++) {
            const int pat = (r & 3) + 8 * (r >> 2);
            rg[r] = qdc[((jcst - pat) & 255) * 72];
        }
        bf8 vf00 = *(const bf8*)&Vb[cur][l31][wt * 32 + hi * 8];
        bf8 vf01 = *(const bf8*)&Vb[cur][l31][wt * 32 + 16 + hi * 8];
        bf8 vf10 = *(const bf8*)&Vb[cur][32 + l31][wt * 32 + hi * 8];
        bf8 vf11 = *(const bf8*)&Vb[cur][32 + l31][wt * 32 + 16 + hi * 8];

        // ---- QK^T, swapped; SPLIT into two 2-deep accumulator chains ----
        __builtin_amdgcn_s_setprio(1);
        f16v sA, sB;
        #pragma unroll
        for (int r = 0; r < 16; r++) { sA[r] = 0.f; sB[r] = 0.f; }
        sA = MFMA32(ka[0], qb[0], sA);
        sB = MFMA32(ka[1], qb[1], sB);
        sA = MFMA32(ka[2], qb[2], sA);
        sB = MFMA32(ka[3], qb[3], sB);
        __builtin_amdgcn_s_setprio(0);

        // ---- softmax half 0 -> pa0 -> 2 PV MFMAs ----
        float p[16];
        float la = 0.f, lb = 0.f;
        #pragma unroll
        for (int r = 0; r < 8; r++) {
            float pv = fexp2(sA[r] + (sB[r] + b2f(rg[r])));
            p[r] = pv; la += pv;
        }
        unsigned w00 = cvtpk_bf16(p[0], p[1]), w01 = cvtpk_bf16(p[2], p[3]);
        unsigned w10 = cvtpk_bf16(p[4], p[5]), w11 = cvtpk_bf16(p[6], p[7]);
        swap32(w00, w10); swap32(w01, w11);
        union { unsigned u[4]; bf8 v; } pa0, pa1;
        pa0.u[0] = w00; pa0.u[1] = w01; pa0.u[2] = w10; pa0.u[3] = w11;
        __builtin_amdgcn_s_setprio(1);
        oo[0] = MFMA32(pa0.v, vf00, oo[0]);
        oo[1] = MFMA32(pa0.v, vf10, oo[1]);
        __builtin_amdgcn_s_setprio(0);

        // ---- mid-iter commit of next K/V tile (off the pre-barrier tail) ----
        if (pre) {
            *(bf8*)&Kb[nxt][sr][sc]      = kr0;
            *(bf8*)&Kb[nxt][sr + 32][sc] = kr1;
            *(bf8*)&Vb[nxt][sr][sc]      = vr0;
            *(bf8*)&Vb[nxt][sr + 32][sc] = vr1;
        }
        // ---- refresh: SPLIT 2+2 chains, completes under sm1/PV1 ----
        f16v rfA, rfB;
        if (pre) {
            #pragma unroll
            for (int r = 0; r < 16; r++) { rfA[r] = 0.f; rfB[r] = 0.f; }
            rfA = MFMA32(qb[0], pj0, rfA);
            rfB = MFMA32(qb[1], pj1, rfB);
            rfA = MFMA32(qb[2], pj2, rfA);
            rfB = MFMA32(qb[3], pj3, rfB);
        }

        // ---- softmax half 1 -> pa1 -> 2 PV MFMAs ----
        #pragma unroll
        for (int r = 8; r < 16; r++) {
            float pv = fexp2(sA[r] + (sB[r] + b2f(rg[r])));
            p[r] = pv; lb += pv;
        }
        unsigned w20 = cvtpk_bf16(p[8],  p[9]),  w21 = cvtpk_bf16(p[10], p[11]);
        unsigned w30 = cvtpk_bf16(p[12], p[13]), w31 = cvtpk_bf16(p[14], p[15]);
        swap32(w20, w30); swap32(w21, w31);
        pa1.u[0] = w20; pa1.u[1] = w21; pa1.u[2] = w30; pa1.u[3] = w31;
        __builtin_amdgcn_s_setprio(1);
        oo[0] = MFMA32(pa1.v, vf01, oo[0]);
        oo[1] = MFMA32(pa1.v, vf11, oo[1]);
        __builtin_amdgcn_s_setprio(0);
        l_lane += la + lb;

        // ---- tail: ring b64 writes only (rfA+rfB combine hides here) ----
        if (pre) {
            #pragma unroll
            for (int o4 = 0; o4 < 4; o4++) {
                bf4 pk;
                #pragma unroll
                for (int r = 0; r < 4; r++)
                    pk[r] = (__bf16)(rfA[o4 * 4 + r] + rfB[o4 * 4 + r]);
                *(bf4*)&Qd[jrn & 255][wq * 32 + o4 * 8 + hi * 4] = pk;
            }
        }
        __syncthreads();   // single barrier: staging visible, buffers released
    }

    // ---- epilogue: cross-half l, cross-wave O reduce (ring LDS reused),
    //      normalize, store ----
    float lsum = l_lane + __shfl_xor(l_lane, 32);
    float* Os = (float*)&Qd[0][0];          // ring is dead; reuse as scratch
    float* Ls = Os + 4096;
    if (lane < 32) Ls[(wq * 2 + wt) * 32 + l31] = lsum;
    if (wt == 0) {
        #pragma unroll
        for (int dt = 0; dt < 2; dt++)
            #pragma unroll
            for (int r = 0; r < 16; r++) {
                const int q = (r & 3) + 8 * (r >> 2) + 4 * hi;
                Os[(wq * 32 + q) * 64 + dt * 32 + l31] = oo[dt][r];
            }
    }
    __syncthreads();
    if (wt == 1) {
        const int h = bh & 7;
        #pragma unroll
        for (int r = 0; r < 16; r++) {
            const int q = (r & 3) + 8 * (r >> 2) + 4 * hi;
            const float li = 1.f / (Ls[wq * 64 + q] + Ls[wq * 64 + 32 + q]);
            #pragma unroll
            for (int dt = 0; dt < 2; dt++) {
                float v = (oo[dt][r] + Os[(wq * 32 + q) * 64 + dt * 32 + l31]) * li;
                ctxb[(size_t)(b * SEQ + s0 + wq * 32 + q) * DM + h * HD + dt * 32 + l31]
                    = (__bf16)v;
            }
        }
    }
}

// ---------------------------------------------------------------------------
extern "C" void kernel_launch(void* const* d_in, const int* in_sizes, int n_in,
                              void* d_out, int out_size, void* d_ws, size_t ws_size,
                              hipStream_t stream) {
    const float* x    = (const float*)d_in[0];
    // d_in[1] attn_mask: unused by the reference computation
    const float* Wq   = (const float*)d_in[2];
    const float* Wkv  = (const float*)d_in[3];
    const float* Wout = (const float*)d_in[4];
    const float* bout = (const float*)d_in[5];
    const float* pemb = (const float*)d_in[6];
    float* out = (float*)d_out;

    const int M = BATCH * SEQ;   // 4096
    u16* p = (u16*)d_ws;
    u16* xb    = p; p += (size_t)M * DM;          // 4096x512
    u16* qkvw  = p; p += (size_t)NQKV * DM;       // 1536x512 (Wq^T ++ Wkv^T)
    u16* Woutt = p; p += (size_t)DM * DM;         // 512x512
    u16* pembb = p; p += (size_t)1025 * HD;       // 1025x64
    u16* qtb   = p; p += (size_t)M * DM;          // 32x1024x64 packed q (scaled)
    u16* ktb   = p; p += (size_t)M * DM;          // 32x1024x64 packed K
    u16* vtb   = p; p += (size_t)M * DM;          // 32x64x1024 transposed V
    u16* ctxb  = p; p += (size_t)M * DM;          // 4096x512

    prep<<<3137, 256, 0, stream>>>(x, Wq, Wkv, Wout, pemb, xb, qkvw, Woutt, pembb);

    // QKV projection with fused q-scale / K-pack / V-transpose epilogue
    gemm_bt<128><<<dim3(NQKV / 128, M / 64), 256, 0, stream>>>(
        xb, qkvw, M, NQKV, DM, nullptr, nullptr,
        (__bf16*)qtb, (__bf16*)ktb, (__bf16*)vtb);

    // fused attention -> ctx; grid x=bh for XCD L2 locality
    attn_mfma<<<dim3(BATCH * NH, SEQ / 64), 256, 0, stream>>>(
        qtb, ktb, vtb, pembb, (__bf16*)ctxb);

    // out = ctx @ Wout + bout  (BN=64: 512 blocks = 2/CU vs 1/CU at BN=128)
    gemm_bt<64><<<dim3(DM / 64, M / 64), 256, 0, stream>>>(
        ctxb, Woutt, M, DM, DM, out, bout, nullptr, nullptr, nullptr);
}

// Round 12
// 125.058 us; speedup vs baseline: 1.1460x; 1.0195x over previous
//
#include <hip/hip_runtime.h>
#include <hip/hip_bf16.h>

constexpr int BATCH = 4;
constexpr int SEQ   = 1024;
constexpr int DM    = 512;     // model dim = HEADS*HDIM
constexpr int NH    = 8;
constexpr int HD    = 64;
constexpr int NQKV  = 1536;    // q(512) + k(512) + v(512) fused projection width

typedef unsigned short u16;
typedef __attribute__((ext_vector_type(8))) __bf16 bf8;
typedef __attribute__((ext_vector_type(4))) __bf16 bf4;
typedef __attribute__((ext_vector_type(4))) float  f4;
typedef __attribute__((ext_vector_type(16))) float f16v;

#define MFMA16(a, b, c) __builtin_amdgcn_mfma_f32_16x16x32_bf16(a, b, c, 0, 0, 0)
#define MFMA32(a, b, c) __builtin_amdgcn_mfma_f32_32x32x16_bf16(a, b, c, 0, 0, 0)

// 0.125 (1/sqrt(64)) * log2(e): q pre-scale so softmax uses exp2 directly
#define QSC 0.18033688f

static __device__ __forceinline__ u16 f2b(float f) {
    union { float f; unsigned u; } v; v.f = f;
    unsigned r = v.u + 0x7FFFu + ((v.u >> 16) & 1u);   // RNE; inputs never NaN
    return (u16)(r >> 16);
}
static __device__ __forceinline__ float b2f(u16 x) {
    union { unsigned u; float f; } v; v.u = (unsigned)x << 16;   // bf16->f32 exact
    return v.f;
}
static __device__ __forceinline__ float fexp2(float x) {
    return __builtin_amdgcn_exp2f(x);
}
// async global->LDS, 16 B per lane (dst = wave-uniform base + lane*16)
static __device__ __forceinline__ void gl_lds16(const void* g, void* l) {
    __builtin_amdgcn_global_load_lds(
        (const __attribute__((address_space(1))) void*)g,
        (__attribute__((address_space(3))) void*)l, 16, 0, 0);
}
// pack two f32 -> one u32 of 2 bf16 (RNE), single VOP3
static __device__ __forceinline__ unsigned cvtpk_bf16(float lo, float hi) {
    unsigned r;
    asm("v_cvt_pk_bf16_f32 %0, %1, %2" : "=v"(r) : "v"(lo), "v"(hi));
    return r;
}
// swap a's hi-32-lane half with b's lo-32-lane half
static __device__ __forceinline__ void swap32(unsigned &a, unsigned &b) {
    asm("v_permlane32_swap_b32 %0, %1" : "+v"(a), "+v"(b));
}

// ---------------------------------------------------------------------------
// Fused prep: one launch does all fp32->bf16 converts + weight transposes.
// ---------------------------------------------------------------------------
__device__ __forceinline__ void tcvt_tile(const float* __restrict__ in,
                                          u16* __restrict__ out,
                                          int R, int C, int bx, int by, int tid,
                                          float (*t)[33]) {
    int r0 = by * 32, c0 = bx * 32;
    int lc = tid & 31, lr = tid >> 5;   // lr in [0,8)
    #pragma unroll
    for (int p = 0; p < 4; p++) {
        int r = lr + p * 8;
        t[r][lc] = in[(size_t)(r0 + r) * C + c0 + lc];
    }
    __syncthreads();
    #pragma unroll
    for (int p = 0; p < 4; p++) {
        int r = lr + p * 8;
        out[(size_t)(c0 + r) * R + r0 + lc] = f2b(t[lc][r]);
    }
}

__global__ __launch_bounds__(256)
void prep(const float* __restrict__ x, const float* __restrict__ Wq,
          const float* __restrict__ Wkv, const float* __restrict__ Wout,
          const float* __restrict__ pemb,
          u16* __restrict__ xb, u16* __restrict__ qkvw,
          u16* __restrict__ Woutt, u16* __restrict__ pembb) {
    __shared__ float t[32][33];
    const int blk = blockIdx.x, tid = threadIdx.x;
    if (blk < 2048) {
        int i = (blk * 256 + tid) * 4;
        float4 v = *(const float4*)(x + i);
        ushort4 o = {f2b(v.x), f2b(v.y), f2b(v.z), f2b(v.w)};
        *(ushort4*)(xb + i) = o;
    } else if (blk < 2113) {
        int i = ((blk - 2048) * 256 + tid) * 4;
        if (i < 1025 * HD) {
            float4 v = *(const float4*)(pemb + i);
            ushort4 o = {f2b(v.x), f2b(v.y), f2b(v.z), f2b(v.w)};
            *(ushort4*)(pembb + i) = o;
        }
    } else if (blk < 2369) {
        int l = blk - 2113;
        tcvt_tile(Wq, qkvw, 512, 512, l & 15, l >> 4, tid, t);
    } else if (blk < 2881) {
        int l = blk - 2369;
        tcvt_tile(Wkv, qkvw + 512 * 512, 512, 1024, l & 31, l >> 5, tid, t);
    } else {
        int l = blk - 2881;
        tcvt_tile(Wout, Woutt, 512, 512, l & 15, l >> 4, tid, t);
    }
}

// ---------------------------------------------------------------------------
// MFMA GEMM: C[M,N] = A[M,K] @ Bt[N,K]^T  (bf16 in, fp32 acc)
// Templated on BN (tile = 64 x BN). BK=64 as 2x 32-wide sub-tiles (m97
// layout). 256 threads = 4 waves; per-wave output 32 x BN/2.
//   BN=128: QKV projection.  BN=64: output projection (512 blocks = 2/CU).
// Mode 1 (Cf!=null): fp32 out + bias. Mode 2 (qtb/ktb/vtb): QKV packing.
// ---------------------------------------------------------------------------
template<int BN>
__global__ __launch_bounds__(256)
void gemm_bt(const u16* __restrict__ A, const u16* __restrict__ Bt,
             int M, int N, int K,
             float* __restrict__ Cf, const float* __restrict__ bias,
             __bf16* __restrict__ qtb, __bf16* __restrict__ ktb,
             __bf16* __restrict__ vtb) {
    constexpr int NJ = BN / 32;          // B-frags per wave
    __shared__ __align__(16) u16 As[2][64][32];
    __shared__ __align__(16) u16 Bs[2][BN][32];
    const int tid = threadIdx.x, w = tid >> 6, lane = tid & 63;
    const int l15 = lane & 15, l4 = lane >> 4;
    const int wr = (w >> 1) * 32, wc = (w & 1) * (BN / 2);
    const int bm = blockIdx.y * 64, bn = blockIdx.x * BN;

    f4 acc[2][NJ];
    #pragma unroll
    for (int i = 0; i < 2; i++)
        #pragma unroll
        for (int j = 0; j < NJ; j++) acc[i][j] = (f4){0.f, 0.f, 0.f, 0.f};

    const int rS = lane >> 2;          // row within a 16-row staging group
    const int cS = (lane & 3) * 8;     // col (u16) within the 32-wide row

    for (int k0 = 0; k0 < K; k0 += 64) {
        #pragma unroll
        for (int ks = 0; ks < 2; ks++) {
            gl_lds16(A + (size_t)(bm + w * 16 + rS) * K + k0 + ks * 32 + cS,
                     &As[ks][w * 16][0]);
            #pragma unroll
            for (int rb = 0; rb < BN / 4; rb += 16)
                gl_lds16(Bt + (size_t)(bn + w * (BN / 4) + rb + rS) * K
                             + k0 + ks * 32 + cS,
                         &Bs[ks][w * (BN / 4) + rb][0]);
        }
        __syncthreads();
        #pragma unroll
        for (int ks = 0; ks < 2; ks++) {
            bf8 af[2], bf[NJ];
            #pragma unroll
            for (int i = 0; i < 2; i++)
                af[i] = *(const bf8*)&As[ks][wr + i * 16 + l15][l4 * 8];
            #pragma unroll
            for (int j = 0; j < NJ; j++)
                bf[j] = *(const bf8*)&Bs[ks][wc + j * 16 + l15][l4 * 8];
            #pragma unroll
            for (int i = 0; i < 2; i++)
                #pragma unroll
                for (int j = 0; j < NJ; j++)
                    acc[i][j] = MFMA16(af[i], bf[j], acc[i][j]);
        }
        __syncthreads();
    }
    #pragma unroll
    for (int i = 0; i < 2; i++)
        #pragma unroll
        for (int j = 0; j < NJ; j++) {
            const int col = bn + wc + j * 16 + l15;
            const int row0 = bm + wr + i * 16 + l4 * 4;
            if (Cf) {
                #pragma unroll
                for (int reg = 0; reg < 4; reg++)
                    Cf[(size_t)(row0 + reg) * N + col] = acc[i][j][reg] + bias[col];
            } else if (col < 512) {
                int h = col >> 6, d = col & 63;
                #pragma unroll
                for (int reg = 0; reg < 4; reg++) {
                    int row = row0 + reg;
                    int b = row >> 10, t = row & 1023;
                    qtb[((((size_t)(b * 8 + h)) << 10 | t) << 6) | d] =
                        (__bf16)(acc[i][j][reg] * QSC);
                }
            } else if (col < 1024) {
                int h = (col >> 6) - 8, d = col & 63;
                #pragma unroll
                for (int reg = 0; reg < 4; reg++) {
                    int row = row0 + reg;
                    int b = row >> 10, t = row & 1023;
                    ktb[((((size_t)(b * 8 + h)) << 10 | t) << 6) | d] =
                        (__bf16)acc[i][j][reg];
                }
            } else {
                int h = (col >> 6) - 16, d = col & 63;
                int b = row0 >> 10, t = row0 & 1023;   // 4 rows share b (t aligned 4)
                __bf16 pk[4];
                #pragma unroll
                for (int reg = 0; reg < 4; reg++) pk[reg] = (__bf16)acc[i][j][reg];
                *(ushort4*)&vtb[(((size_t)(b * 8 + h) * 64 + d) << 10) | t] =
                    *(ushort4*)pk;
            }
        }
}

// ---------------------------------------------------------------------------
// Fused MFMA flash attention — FINAL: verified-best R7 structure (124.26us
// total). Session conclusions baked into this design:
//  - 32x32 quadrant decomposition, swapped QK^T (mfma32(K,Q)) making softmax
//    lane-local; P->A-frags via 8 cvt_pk + 4 permlane32 (zero LDS round-trip).
//  - K/V LDS staging is a COALESCING+BROADCAST stage, not a copy pipeline:
//    cooperative contiguous-row loads + reg-staged double-buffer beat both
//    gl_lds16 DMA (R5: +4us, vmcnt(0) drain gates the barrier) and direct
//    per-fragment global reads (R10: +20us, 128B/2KB-stride gathers).
//  - All LDS loads hoisted to iteration top (hide under QK^T MFMAs);
//    softmax halves interleaved with PV; mid-iter K/V commit; setprio(1)
//    only around MFMA clusters; pre-barrier tail = 4 ring b64 writes.
//  - qdot ring [j&255][s]: b64 refresh writes, scalar diagonal gather;
//    256 slots keep same-iter read/refresh windows disjoint (race-free
//    with ONE barrier per K-tile).
// Kernel is latency-bound (no pipe >50%), occupancy grid+LDS-capped at
// 8 waves/CU; scheduling variants R5-R11 all neutral or regressed.
// Grid: x = bh (XCD L2 locality), y = s0/64. LDS = 73,728 B -> 2 blocks/CU.
// ---------------------------------------------------------------------------
__global__ __launch_bounds__(256)
void attn_mfma(const u16* __restrict__ qtb, const u16* __restrict__ ktb,
               const u16* __restrict__ vtb, const u16* __restrict__ pembb,
               __bf16* __restrict__ ctxb) {
    __shared__ __align__(16) __bf16 Kb[2][64][72];  // K tiles [t][d]
    __shared__ __align__(16) __bf16 Vb[2][64][72];  // V tiles [d][t]
    __shared__ __align__(16) __bf16 Qd[256][72];    // qdot ring [j&255][s]

    const int tid = threadIdx.x, w = tid >> 6, lane = tid & 63;
    const int l31 = lane & 31, hi = lane >> 5;
    const int wq = w >> 1, wt = w & 1;
    const int bh = blockIdx.x, b = bh >> 3;
    const int s0 = blockIdx.y * 64;

    // Q frags (B-operand for swapped QK^T, A-operand for ring refresh)
    bf8 qb[4];
    {
        const u16* qp = qtb + ((size_t)bh * SEQ + s0 + wq * 32 + l31) * HD + hi * 8;
        #pragma unroll
        for (int st = 0; st < 4; st++) qb[st] = *(const bf8*)(qp + st * 16);
    }

    // ---- init ring: j in [s0+449, +127], wave covers (s=wq-half, j=wt-half)
    #pragma unroll
    for (int pass = 0; pass < 2; pass++) {
        const int jr = s0 + 449 + pass * 64 + wt * 32 + l31;
        const int jc = min(1024, max(0, jr));
        const u16* pp = pembb + (size_t)jc * HD + hi * 8;
        f16v acc;
        #pragma unroll
        for (int r = 0; r < 16; r++) acc[r] = 0.f;
        #pragma unroll
        for (int st = 0; st < 4; st++) {
            bf8 pj = *(const bf8*)(pp + st * 16);
            acc = MFMA32(qb[st], pj, acc);
        }
        #pragma unroll
        for (int o4 = 0; o4 < 4; o4++) {
            bf4 pk;
            #pragma unroll
            for (int r = 0; r < 4; r++) pk[r] = (__bf16)acc[o4 * 4 + r];
            *(bf4*)&Qd[jr & 255][wq * 32 + o4 * 8 + hi * 4] = pk;
        }
    }

    float l_lane = 0.f;
    f16v oo[2];
    #pragma unroll
    for (int dt = 0; dt < 2; dt++)
        #pragma unroll
        for (int r = 0; r < 16; r++) oo[dt][r] = 0.f;

    const u16* kbase = ktb + (size_t)bh * SEQ * HD;   // [t][d] packed
    const u16* vbase = vtb + (size_t)bh * HD * SEQ;   // [d][t]
    const int sr = tid >> 3, sc = (tid & 7) * 8;

    // ---- stage tile 0 into buf 0 ----
    *(bf8*)&Kb[0][sr][sc]      = *(const bf8*)(kbase + (size_t)sr * HD + sc);
    *(bf8*)&Kb[0][sr + 32][sc] = *(const bf8*)(kbase + (size_t)(sr + 32) * HD + sc);
    *(bf8*)&Vb[0][sr][sc]      = *(const bf8*)(vbase + (size_t)sr * SEQ + sc);
    *(bf8*)&Vb[0][sr + 32][sc] = *(const bf8*)(vbase + (size_t)(sr + 32) * SEQ + sc);
    __syncthreads();

    for (int i = 0; i < 16; i++) {
        const int cur = i & 1, nxt = cur ^ 1;
        const int t0 = i * 64, t1 = t0 + 64;
        const bool pre = (i < 15);
        bf8 kr0, kr1, vr0, vr1, pj0, pj1, pj2, pj3;
        const int jrn = s0 + 449 - 64 * (i + 1) + wt * 32 + l31;
        if (pre) {
            kr0 = *(const bf8*)(kbase + (size_t)(t1 + sr) * HD + sc);
            kr1 = *(const bf8*)(kbase + (size_t)(t1 + sr + 32) * HD + sc);
            vr0 = *(const bf8*)(vbase + (size_t)sr * SEQ + t1 + sc);
            vr1 = *(const bf8*)(vbase + (size_t)(sr + 32) * SEQ + t1 + sc);
            const int jc = min(1024, max(0, jrn));
            const u16* pp = pembb + (size_t)jc * HD + hi * 8;
            pj0 = *(const bf8*)(pp);
            pj1 = *(const bf8*)(pp + 16);
            pj2 = *(const bf8*)(pp + 32);
            pj3 = *(const bf8*)(pp + 48);
        }

        // ---- ALL LDS loads up front: K-frags, ring gather, V-frags ----
        bf8 ka[4];
        #pragma unroll
        for (int st = 0; st < 4; st++)
            ka[st] = *(const bf8*)&Kb[cur][wt * 32 + l31][st * 16 + hi * 8];
        const int jcst = (s0 - t0 + 512) + wq * 32 + l31 - wt * 32 - 4 * hi;
        const u16* qdc = (const u16*)&Qd[0][0] + wq * 32 + l31;
        u16 rg[16];
        #pragma unroll
        for (int r = 0; r < 16; r++) {
            const int pat = (r & 3) + 8 * (r >> 2);
            rg[r] = qdc[((jcst - pat) & 255) * 72];
        }
        bf8 vf00 = *(const bf8*)&Vb[cur][l31][wt * 32 + hi * 8];
        bf8 vf01 = *(const bf8*)&Vb[cur][l31][wt * 32 + 16 + hi * 8];
        bf8 vf10 = *(const bf8*)&Vb[cur][32 + l31][wt * 32 + hi * 8];
        bf8 vf11 = *(const bf8*)&Vb[cur][32 + l31][wt * 32 + 16 + hi * 8];

        // ---- QK^T, swapped: lane holds q = wq*32+l31, 16 t's of wt-half ----
        __builtin_amdgcn_s_setprio(1);
        f16v s16;
        #pragma unroll
        for (int r = 0; r < 16; r++) s16[r] = 0.f;
        #pragma unroll
        for (int st = 0; st < 4; st++) s16 = MFMA32(ka[st], qb[st], s16);
        __builtin_amdgcn_s_setprio(0);

        // ---- softmax half 0 -> pa0 -> 2 PV MFMAs ----
        float p[16];
        float la = 0.f, lb = 0.f;
        #pragma unroll
        for (int r = 0; r < 8; r++) {
            float pv = fexp2(s16[r] + b2f(rg[r]));
            p[r] = pv; la += pv;
        }
        unsigned w00 = cvtpk_bf16(p[0], p[1]), w01 = cvtpk_bf16(p[2], p[3]);
        unsigned w10 = cvtpk_bf16(p[4], p[5]), w11 = cvtpk_bf16(p[6], p[7]);
        swap32(w00, w10); swap32(w01, w11);
        union { unsigned u[4]; bf8 v; } pa0, pa1;
        pa0.u[0] = w00; pa0.u[1] = w01; pa0.u[2] = w10; pa0.u[3] = w11;
        __builtin_amdgcn_s_setprio(1);
        oo[0] = MFMA32(pa0.v, vf00, oo[0]);
        oo[1] = MFMA32(pa0.v, vf10, oo[1]);
        __builtin_amdgcn_s_setprio(0);

        // ---- mid-iter commit of next K/V tile (off the pre-barrier tail;
        //      vmcnt distance from top-of-iter loads ~= QK^T + sm0) ----
        if (pre) {
            *(bf8*)&Kb[nxt][sr][sc]      = kr0;
            *(bf8*)&Kb[nxt][sr + 32][sc] = kr1;
            *(bf8*)&Vb[nxt][sr][sc]      = vr0;
            *(bf8*)&Vb[nxt][sr + 32][sc] = vr1;
        }
        // ---- refresh MFMA chain starts here, completes under sm1/PV1 ----
        f16v rf;
        if (pre) {
            #pragma unroll
            for (int r = 0; r < 16; r++) rf[r] = 0.f;
            rf = MFMA32(qb[0], pj0, rf);
            rf = MFMA32(qb[1], pj1, rf);
            rf = MFMA32(qb[2], pj2, rf);
            rf = MFMA32(qb[3], pj3, rf);
        }

        // ---- softmax half 1 -> pa1 -> 2 PV MFMAs ----
        #pragma unroll
        for (int r = 8; r < 16; r++) {
            float pv = fexp2(s16[r] + b2f(rg[r]));
            p[r] = pv; lb += pv;
        }
        unsigned w20 = cvtpk_bf16(p[8],  p[9]),  w21 = cvtpk_bf16(p[10], p[11]);
        unsigned w30 = cvtpk_bf16(p[12], p[13]), w31 = cvtpk_bf16(p[14], p[15]);
        swap32(w20, w30); swap32(w21, w31);
        pa1.u[0] = w20; pa1.u[1] = w21; pa1.u[2] = w30; pa1.u[3] = w31;
        __builtin_amdgcn_s_setprio(1);
        oo[0] = MFMA32(pa1.v, vf01, oo[0]);
        oo[1] = MFMA32(pa1.v, vf11, oo[1]);
        __builtin_amdgcn_s_setprio(0);
        l_lane += la + lb;

        // ---- tail: only the ring b64 writes remain ----
        if (pre) {
            #pragma unroll
            for (int o4 = 0; o4 < 4; o4++) {
                bf4 pk;
                #pragma unroll
                for (int r = 0; r < 4; r++) pk[r] = (__bf16)rf[o4 * 4 + r];
                *(bf4*)&Qd[jrn & 255][wq * 32 + o4 * 8 + hi * 4] = pk;
            }
        }
        __syncthreads();   // single barrier: staging visible, buffers released
    }

    // ---- epilogue: cross-half l, cross-wave O reduce (ring LDS reused),
    //      normalize, store ----
    float lsum = l_lane + __shfl_xor(l_lane, 32);
    float* Os = (float*)&Qd[0][0];          // ring is dead; reuse as scratch
    float* Ls = Os + 4096;
    if (lane < 32) Ls[(wq * 2 + wt) * 32 + l31] = lsum;
    if (wt == 0) {
        #pragma unroll
        for (int dt = 0; dt < 2; dt++)
            #pragma unroll
            for (int r = 0; r < 16; r++) {
                const int q = (r & 3) + 8 * (r >> 2) + 4 * hi;
                Os[(wq * 32 + q) * 64 + dt * 32 + l31] = oo[dt][r];
            }
    }
    __syncthreads();
    if (wt == 1) {
        const int h = bh & 7;
        #pragma unroll
        for (int r = 0; r < 16; r++) {
            const int q = (r & 3) + 8 * (r >> 2) + 4 * hi;
            const float li = 1.f / (Ls[wq * 64 + q] + Ls[wq * 64 + 32 + q]);
            #pragma unroll
            for (int dt = 0; dt < 2; dt++) {
                float v = (oo[dt][r] + Os[(wq * 32 + q) * 64 + dt * 32 + l31]) * li;
                ctxb[(size_t)(b * SEQ + s0 + wq * 32 + q) * DM + h * HD + dt * 32 + l31]
                    = (__bf16)v;
            }
        }
    }
}

// ---------------------------------------------------------------------------
extern "C" void kernel_launch(void* const* d_in, const int* in_sizes, int n_in,
                              void* d_out, int out_size, void* d_ws, size_t ws_size,
                              hipStream_t stream) {
    const float* x    = (const float*)d_in[0];
    // d_in[1] attn_mask: unused by the reference computation
    const float* Wq   = (const float*)d_in[2];
    const float* Wkv  = (const float*)d_in[3];
    const float* Wout = (const float*)d_in[4];
    const float* bout = (const float*)d_in[5];
    const float* pemb = (const float*)d_in[6];
    float* out = (float*)d_out;

    const int M = BATCH * SEQ;   // 4096
    u16* p = (u16*)d_ws;
    u16* xb    = p; p += (size_t)M * DM;          // 4096x512
    u16* qkvw  = p; p += (size_t)NQKV * DM;       // 1536x512 (Wq^T ++ Wkv^T)
    u16* Woutt = p; p += (size_t)DM * DM;         // 512x512
    u16* pembb = p; p += (size_t)1025 * HD;       // 1025x64
    u16* qtb   = p; p += (size_t)M * DM;          // 32x1024x64 packed q (scaled)
    u16* ktb   = p; p += (size_t)M * DM;          // 32x1024x64 packed K
    u16* vtb   = p; p += (size_t)M * DM;          // 32x64x1024 transposed V
    u16* ctxb  = p; p += (size_t)M * DM;          // 4096x512

    prep<<<3137, 256, 0, stream>>>(x, Wq, Wkv, Wout, pemb, xb, qkvw, Woutt, pembb);

    // QKV projection with fused q-scale / K-pack / V-transpose epilogue
    gemm_bt<128><<<dim3(NQKV / 128, M / 64), 256, 0, stream>>>(
        xb, qkvw, M, NQKV, DM, nullptr, nullptr,
        (__bf16*)qtb, (__bf16*)ktb, (__bf16*)vtb);

    // fused attention -> ctx; grid x=bh for XCD L2 locality
    attn_mfma<<<dim3(BATCH * NH, SEQ / 64), 256, 0, stream>>>(
        qtb, ktb, vtb, pembb, (__bf16*)ctxb);

    // out = ctx @ Wout + bout  (BN=64: 512 blocks = 2/CU vs 1/CU at BN=128)
    gemm_bt<64><<<dim3(DM / 64, M / 64), 256, 0, stream>>>(
        ctxb, Woutt, M, DM, DM, out, bout, nullptr, nullptr, nullptr);
}